// Round 12
// baseline (388.707 us; speedup 1.0000x reference)
//
#include <hip/hip_runtime.h>
#include <cstdint>
#include <cstddef>

typedef unsigned int u32;
typedef unsigned long long u64;

#define BB   8
#define NN   50000
#define CC   80
#define KTOP 1000
#define CAP  4096
#define NHB  129              // 128 fine buckets [0x3F00..0x3F7F] + 1 underflow
#define CLIPV 4.135166556742356f

// ---- workspace layout (bytes), total ~4.71 MB ----
#define OFF_KEYS 0UL          // u32 [B*N]
#define OFF_CLS  1600000UL    // i32 [B*N]
#define OFF_HIST 3200000UL    // u32 [B*129]
#define OFF_CNT  3204128UL    // u32 [B*16] (64-B stride per image)
#define OFF_CAND 3204640UL    // u64 [B*CAP]
#define OFF_TKEY 3466784UL    // u32 [B*K]
#define OFF_TIDX 3498784UL    // u32 [B*K]
#define OFF_BOX  3530784UL    // f32 [B*K*4]
#define OFF_AREA 3658784UL    // f32 [B*K]
#define OFF_MAT  3690784UL    // u64 [B*K*16]

// Pass 1: LDS-staged coalesced max/argmax + LDS histogram, aggregated flush.
// Grid: 8 images x 196 blocks; 256 thr; 4 tiles x 64 anchors.
__global__ __launch_bounds__(256) void k_scores_u(const float4* __restrict__ labels4,
                                                  u32* __restrict__ keys,
                                                  int* __restrict__ cls,
                                                  u32* __restrict__ ghist) {
    __shared__ float4 tile[64 * 21];          // pad-21: stage s -> s + s/20
    __shared__ float  pbest[3][64];
    __shared__ int    pcls[3][64];
    __shared__ u32    lhist[NHB];
    int t = threadIdx.x;
    int img = blockIdx.x / 196;
    int blk = blockIdx.x - img * 196;
    size_t img_base = (size_t)img * NN * 20;  // float4 units
    for (int i = t; i < NHB; i += 256) lhist[i] = 0;
    int a = t & 63;
    int q = t >> 6;
#pragma unroll
    for (int tl = 0; tl < 4; ++tl) {
        int na0 = blk * 256 + tl * 64;
        int nv = NN - na0; if (nv > 64) nv = 64; if (nv < 0) nv = 0;
        int lim = nv * 20;
#pragma unroll
        for (int i = 0; i < 5; ++i) {
            int s = i * 256 + t;
            if (s < lim) {
                float4 v = labels4[img_base + (size_t)na0 * 20 + s];
                tile[s + s / 20] = v;
            }
        }
        __syncthreads();
        float best = -1.0e30f; int bc = 0;
        if (a < nv) {
#pragma unroll
            for (int j = 0; j < 5; ++j) {
                float4 v = tile[a * 21 + q * 5 + j];
                int c = q * 20 + j * 4;
                if (v.x > best) { best = v.x; bc = c; }
                if (v.y > best) { best = v.y; bc = c + 1; }
                if (v.z > best) { best = v.z; bc = c + 2; }
                if (v.w > best) { best = v.w; bc = c + 3; }
            }
            if (q > 0) { pbest[q - 1][a] = best; pcls[q - 1][a] = bc; }
        }
        __syncthreads();
        if (q == 0 && a < nv) {
#pragma unroll
            for (int r = 0; r < 3; ++r) {     // ascending class order, strict >
                float pb = pbest[r][a];
                if (pb > best) { best = pb; bc = pcls[r][a]; }
            }
            int g = img * NN + na0 + a;
            float score = 1.0f / (1.0f + expf(-best));
            bool fg = (bc != 0) && (score > 0.05f);
            u32 key = fg ? __float_as_uint(score) : 0u;
            keys[g] = key;
            cls[g] = bc;
            u32 kb = key >> 16;
            u32 idx = (kb >= 0x3F00u) ? (kb - 0x3F00u) : 128u;
            atomicAdd(&lhist[idx], 1u);
        }
        __syncthreads();
    }
    for (int i = t; i < NHB; i += 256) {
        u32 c = lhist[i];
        if (c) atomicAdd(&ghist[img * NHB + i], c);
    }
}

// Pass 2: candidate compaction, with in-block threshold computation.
// Threads 0..127 shfl-scan the 128 fine buckets (desc order) to find T16;
// then ballot prefix-sum compaction with ONE atomicAdd per block.
__global__ __launch_bounds__(256) void k_gather(const u32* __restrict__ keys,
                                                const u32* __restrict__ ghist,
                                                u32* __restrict__ cnt,
                                                u64* __restrict__ cand) {
    __shared__ u32 wsum[4];
    __shared__ u32 bbase;
    __shared__ u32 sT16;
    __shared__ u32 wtot;
    int t = threadIdx.x;
    int img = blockIdx.x / 196;
    int blk = blockIdx.x - img * 196;

    // --- threshold: descending cumulative over buckets 127..0 ---
    u32 v = 0;
    if (t < 128) v = ghist[img * NHB + (127 - t)];   // tid asc == bucket desc
    u32 incl = v;
#pragma unroll
    for (int d = 1; d < 64; d <<= 1) {
        u32 up = __shfl_up(incl, (unsigned)d);       // width 64
        if ((t & 63) >= d) incl += up;
    }
    if (t == 63) wtot = incl;
    __syncthreads();
    if (t >= 64 && t < 128) incl += wtot;
    if (t < 128) {
        u32 excl = incl - v;
        if (excl < KTOP && incl >= KTOP) sT16 = 0x3F00u + 127u - (u32)t;  // unique crossing
    }
    if (t == 127 && incl < KTOP) sT16 = 0x3F00u;     // total < K: take all fine buckets
    __syncthreads();
    u32 T16 = sT16;

    // --- compaction ---
    int n = blk * 256 + t;
    u32 key = 0; bool pass = false;
    if (n < NN) {
        key = keys[img * NN + n];
        pass = (key >> 16) >= T16;
    }
    u64 mask = __ballot(pass);
    int lane = t & 63, wid = t >> 6;
    u32 prefix = (u32)__popcll(mask & ((1ull << lane) - 1ull));
    if (lane == 0) wsum[wid] = (u32)__popcll(mask);
    __syncthreads();
    if (t == 0) {
        u32 s0 = wsum[0], s1 = wsum[1], s2 = wsum[2], s3 = wsum[3];
        u32 tot = s0 + s1 + s2 + s3;
        bbase = tot ? atomicAdd(&cnt[img * 16], tot) : 0u;
        wsum[0] = 0; wsum[1] = s0; wsum[2] = s0 + s1; wsum[3] = s0 + s1 + s2;
    }
    __syncthreads();
    if (pass) {
        u32 pos = bbase + wsum[wid] + prefix;
        if (pos < CAP)
            cand[(size_t)img * CAP + pos] = ((u64)key << 32) | (u32)(~(u32)n); // ~n: idx-asc ties
    }
}

// Pass 3a: bitonic stages k=2..1024, chunk-local. Grid: 8 images x 4 chunks,
// 256 thr x 4 elems. Direction uses the GLOBAL index (base+i) so the split
// network is identical to the monolithic one.
__global__ __launch_bounds__(256) void k_sortA(u64* __restrict__ cand,
                                               const u32* __restrict__ cnt) {
    __shared__ u64 sm[1024];
    int b = blockIdx.x >> 2;
    int c = blockIdx.x & 3;
    int tid = threadIdx.x;
    int m = (int)min(cnt[b * 16], (u32)CAP);
    int base = c * 1024;
    u64* cp = cand + (size_t)b * CAP;
    for (int i = tid; i < 1024; i += 256) {
        int g = base + i;
        sm[i] = (g < m) ? cp[g] : 0ull;
    }
    __syncthreads();
    for (int k = 2; k <= 1024; k <<= 1)
        for (int j = k >> 1; j > 0; j >>= 1) {
            for (int i = tid; i < 1024; i += 256) {
                int ixj = i ^ j;
                if (ixj > i) {
                    bool desc = (((base + i) & k) == 0);
                    u64 x = sm[i], y = sm[ixj];
                    if (desc ? (x < y) : (x > y)) { sm[i] = y; sm[ixj] = x; }
                }
            }
            __syncthreads();
        }
    for (int i = tid; i < 1024; i += 256) cp[base + i] = sm[i];
}

// Pass 3b: merge stages k=2048,4096 (23 steps) + top-K emit + box decode.
// 8 blocks x 512 thr x 8 elems.
__global__ __launch_bounds__(512) void k_sortB(const u64* __restrict__ cand,
                                               const float4* __restrict__ codes,
                                               const float4* __restrict__ anchors,
                                               u32* __restrict__ tkey, u32* __restrict__ tidx,
                                               float4* __restrict__ boxes, float* __restrict__ area) {
    __shared__ u64 sm[CAP];
    int b = blockIdx.x, tid = threadIdx.x;
    const u64* cp = cand + (size_t)b * CAP;
    for (int i = tid; i < CAP; i += 512) sm[i] = cp[i];   // A wrote padded zeros
    __syncthreads();
    for (int k = 2048; k <= 4096; k <<= 1)
        for (int j = k >> 1; j > 0; j >>= 1) {
            for (int i = tid; i < CAP; i += 512) {
                int ixj = i ^ j;
                if (ixj > i) {
                    bool desc = ((i & k) == 0);
                    u64 x = sm[i], y = sm[ixj];
                    if (desc ? (x < y) : (x > y)) { sm[i] = y; sm[ixj] = x; }
                }
            }
            __syncthreads();
        }
#pragma unroll
    for (int r = 0; r < 2; ++r) {
        int i = r * 512 + tid;
        if (i < KTOP) {
            u64 v = sm[i];
            u32 kb = (u32)(v >> 32);
            u32 n = ~(u32)v;
            if (kb == 0u) n = 0u;
            int g = b * KTOP + i;
            tkey[g] = kb; tidx[g] = n;
            float4 a = anchors[(size_t)b * NN + n];
            float4 cc = codes[(size_t)b * NN + n];
            float w = a.z - a.x, h = a.w - a.y;
            float cx = a.x + 0.5f * w, cy = a.y + 0.5f * h;
            float dw = fminf(cc.z, CLIPV), dh = fminf(cc.w, CLIPV);
            float pcx = cc.x * w + cx, pcy = cc.y * h + cy;
            float pw = expf(dw) * w, ph = expf(dh) * h;
            float x0 = pcx - 0.5f * pw, y0 = pcy - 0.5f * ph;
            float x1 = pcx + 0.5f * pw, y1 = pcy + 0.5f * ph;
            boxes[g] = make_float4(x0, y0, x1, y1);
            area[g] = (x1 - x0) * (y1 - y0);
        }
    }
}

// Pass 4: suppression bit-matrix via LDS-staged j-chunks (128 blocks).
__global__ __launch_bounds__(256) void k_mat(const float4* __restrict__ boxes,
                                             const float* __restrict__ area,
                                             u64* __restrict__ mat) {
    __shared__ float4 sb[256];
    __shared__ float  sa[256];
    int bid = blockIdx.x;
    int wc = bid & 3, rc = (bid >> 2) & 3, b = bid >> 4;
    int t = threadIdx.x;
    int j0 = wc * 256;
    int jn = min(256, KTOP - j0);
    if (t < jn) { sb[t] = boxes[b * KTOP + j0 + t]; sa[t] = area[b * KTOP + j0 + t]; }
    __syncthreads();
    if (t >= 250) return;
    int i = rc * 250 + t;
    float4 bi = boxes[b * KTOP + i];
    float ai = area[b * KTOP + i];
    u64 w[4] = {0ull, 0ull, 0ull, 0ull};
    int estart = i - j0 + 1; if (estart < 0) estart = 0;
    for (int e = estart; e < jn; ++e) {
        float4 bj = sb[e];
        float lx = fmaxf(bi.x, bj.x), ly = fmaxf(bi.y, bj.y);
        float rx = fminf(bi.z, bj.z), ry = fminf(bi.w, bj.w);
        float ww = fmaxf(rx - lx, 0.0f), hh = fmaxf(ry - ly, 0.0f);
        float inter = ww * hh;
        float iou = inter / (ai + sa[e] - inter + 1e-9f);
        if (iou > 0.5f) w[e >> 6] |= (1ull << (e & 63));
    }
    u64* outp = &mat[((size_t)(b * KTOP + i)) * 16 + wc * 4];
    outp[0] = w[0]; outp[1] = w[1]; outp[2] = w[2]; outp[3] = w[3];
}

// Pass 5: exact sequential NMS (16 word-phases, one wave) + fused final output.
__global__ __launch_bounds__(64) void k_nmsout(const u64* __restrict__ mat,
                                               const u32* __restrict__ tkey,
                                               const u32* __restrict__ tidx,
                                               const int* __restrict__ cls,
                                               const float4* __restrict__ boxes,
                                               float* __restrict__ out) {
    __shared__ u64 buf[2][1024];
    __shared__ u64 kws[16];
    int b = blockIdx.x, lane = threadIdx.x;
    const u64* mb = mat + (size_t)b * (KTOP * 16);
#pragma unroll
    for (int r = 0; r < 16; ++r) buf[0][r * 64 + lane] = mb[r * 64 + lane];
    __syncthreads();
    u64 kw = 0;
    if (lane < 15) kw = ~0ull;
    else if (lane == 15) kw = (1ull << 40) - 1;   // bits 960..999 valid
    for (int p = 0; p < 16; ++p) {
        int cur = p & 1;
        u64 stg[16];
        if (p < 15) {
#pragma unroll
            for (int r = 0; r < 16; ++r) {
                int idx = (p + 1) * 1024 + r * 64 + lane;
                stg[r] = (idx < KTOP * 16) ? mb[idx] : 0ull;
            }
        }
        u64 applied = 0;
        if (lane == p) {
            for (int c = 0; c < 8; ++c) {
                u64 col[8];
#pragma unroll
                for (int qq = 0; qq < 8; ++qq) col[qq] = buf[cur][(c * 8 + qq) * 16 + p];
#pragma unroll
                for (int qq = 0; qq < 8; ++qq) {
                    int e = c * 8 + qq;
                    if ((kw >> e) & 1ull) { kw &= ~col[qq]; applied |= (1ull << e); }
                }
            }
        }
        applied = __shfl(applied, p);
        if (lane > p && lane < 16) {
            for (int c = 0; c < 8; ++c) {
                u64 col[8];
#pragma unroll
                for (int qq = 0; qq < 8; ++qq) col[qq] = buf[cur][(c * 8 + qq) * 16 + lane];
#pragma unroll
                for (int qq = 0; qq < 8; ++qq)
                    if ((applied >> (c * 8 + qq)) & 1ull) kw &= ~col[qq];
            }
        }
        __syncthreads();
        if (p < 15) {
#pragma unroll
            for (int r = 0; r < 16; ++r) buf[cur ^ 1][r * 64 + lane] = stg[r];
            __syncthreads();
        }
    }
    if (lane < 16) kws[lane] = kw;
    __syncthreads();
    const int BK = BB * KTOP;
#pragma unroll
    for (int r = 0; r < 16; ++r) {
        int k = r * 64 + lane;
        if (k < KTOP) {
            int g = b * KTOP + k;
            bool kp = (kws[k >> 6] >> (k & 63)) & 1ull;
            float sc = __uint_as_float(tkey[g]);
            kp = kp && (sc > 0.0f);
            int cl = cls[(size_t)b * NN + tidx[g]];
            float4 bx = boxes[g];
            out[g] = kp ? (float)cl : -1.0f;                 // out_cls
            out[BK + g] = kp ? sc : 0.0f;                    // out_scores
            float* ob = out + 2 * BK + (size_t)g * 4;        // out_boxes
            ob[0] = kp ? bx.x : 0.0f;
            ob[1] = kp ? bx.y : 0.0f;
            ob[2] = kp ? bx.z : 0.0f;
            ob[3] = kp ? bx.w : 0.0f;
            out[6 * BK + g] = kp ? 1.0f : 0.0f;              // keep
        }
    }
}

extern "C" void kernel_launch(void* const* d_in, const int* in_sizes, int n_in,
                              void* d_out, int out_size, void* d_ws, size_t ws_size,
                              hipStream_t stream) {
    const float* labels  = (const float*)d_in[0];
    const float* codes   = (const float*)d_in[1];
    const float* anchors = (const float*)d_in[2];
    char* ws = (char*)d_ws;
    u32* keys  = (u32*)(ws + OFF_KEYS);
    int* cls   = (int*)(ws + OFF_CLS);
    u32* hist  = (u32*)(ws + OFF_HIST);
    u32* cnt   = (u32*)(ws + OFF_CNT);
    u64* cand  = (u64*)(ws + OFF_CAND);
    u32* tkey  = (u32*)(ws + OFF_TKEY);
    u32* tidx  = (u32*)(ws + OFF_TIDX);
    float4* bx = (float4*)(ws + OFF_BOX);
    float* ar  = (float*)(ws + OFF_AREA);
    u64* mat   = (u64*)(ws + OFF_MAT);

    // zero hist + cnt (4640 B; ws re-poisoned 0xAA before every timed launch)
    hipMemsetAsync(ws + OFF_HIST, 0, OFF_CAND - OFF_HIST, stream);

    k_scores_u<<<BB * 196, 256, 0, stream>>>((const float4*)labels, keys, cls, hist);
    k_gather<<<BB * 196, 256, 0, stream>>>(keys, hist, cnt, cand);
    k_sortA<<<BB * 4, 256, 0, stream>>>(cand, cnt);
    k_sortB<<<BB, 512, 0, stream>>>(cand, (const float4*)codes, (const float4*)anchors,
                                    tkey, tidx, bx, ar);
    k_mat<<<BB * 16, 256, 0, stream>>>(bx, ar, mat);
    k_nmsout<<<BB, 64, 0, stream>>>(mat, tkey, tidx, cls, bx, (float*)d_out);
}